// Round 2
// baseline (84.124 us; speedup 1.0000x reference)
//
#include <hip/hip_runtime.h>

// Problem constants from setup_inputs(): B=8, N=20, K=5, Q=15, D=1024.
#define DCONST 1024
#define KSUP 5
#define NPROTO 20
#define QPER 15
#define SLOTS (KSUP + QPER)   // 20
#define NQ (NPROTO * QPER)    // 300
#define NHALF (NPROTO / 2)    // 10

// ---------------- Kernel 1: proto mean + term_p ----------------
// grid = B*N blocks, 256 threads. Thread t owns d = 4*t .. 4*t+3.
__global__ __launch_bounds__(256) void proto_kernel(
    const float* __restrict__ emb,     // (B, N, K+Q, D)
    const float* __restrict__ weight,  // (4, D) flattened
    float* __restrict__ proto,         // ws: (B*N, D)
    float* __restrict__ term_p)        // ws: (B*N)
{
    const int bn  = blockIdx.x;          // b*N + n
    const int tid = threadIdx.x;
    const int d0  = tid * 4;

    const float* base = emb + ((size_t)bn * SLOTS) * DCONST + d0;
    float4 s = make_float4(0.f, 0.f, 0.f, 0.f);
#pragma unroll
    for (int k = 0; k < KSUP; ++k) {
        float4 v = *reinterpret_cast<const float4*>(base + (size_t)k * DCONST);
        s.x += v.x; s.y += v.y; s.z += v.z; s.w += v.w;
    }
    const float inv = 1.0f / (float)KSUP;
    s.x *= inv; s.y *= inv; s.z *= inv; s.w *= inv;
    *reinterpret_cast<float4*>(proto + (size_t)bn * DCONST + d0) = s;

    // partial dot(proto, w0)
    float4 w0 = *reinterpret_cast<const float4*>(weight + d0);
    float part = s.x * w0.x + s.y * w0.y + s.z * w0.z + s.w * w0.w;

    // wave reduce (64 lanes)
#pragma unroll
    for (int off = 32; off; off >>= 1) part += __shfl_down(part, off, 64);
    __shared__ float red[4];
    const int wid = tid >> 6;
    if ((tid & 63) == 0) red[wid] = part;
    __syncthreads();
    if (tid == 0) term_p[bn] = red[0] + red[1] + red[2] + red[3];
}

// ---------------- Kernel 2: fused logits ----------------
// grid = B * 75 * 2 blocks, 256 threads = 4 waves; each wave owns one query
// row q' and ONE HALF (10) of the protos. Lane l owns d = j*256 + l*4 + {0..3}.
// Per-lane acc[10] keeps all cross-lane reduces out of the hot loop: at the
// end we run 10 independent butterfly trees (throughput-bound, not a serial
// latency chain per n), then lanes 0..9 emit a coalesced 10-float store.
__global__ __launch_bounds__(256, 4) void logits_kernel(
    const float* __restrict__ emb,     // (B, N, K+Q, D)
    const float* __restrict__ weight,  // (4, D)
    const float* __restrict__ bias,    // (1,)
    const float* __restrict__ proto,   // ws: (B*N, D)
    const float* __restrict__ term_p,  // ws: (B*N)
    float* __restrict__ out)           // (B, N*Q, NPROTO)
{
    const int tid  = threadIdx.x;
    const int lane = tid & 63;
    const int wid  = tid >> 6;
    const int half = blockIdx.x & 1;            // which 10 protos
    const int grp  = blockIdx.x >> 1;
    const int blocks_per_b = NQ / 4;            // 75
    const int b  = grp / blocks_per_b;
    const int qp = (grp % blocks_per_b) * 4 + wid;   // 0..299
    const int nsrc = qp / QPER;
    const int qq   = qp % QPER;

    const float* qrow =
        emb + (((size_t)(b * NPROTO + nsrc) * SLOTS) + KSUP + qq) * DCONST;

    float4 q4[4], w2r[4], qw3[4];
    float tq = 0.f;
#pragma unroll
    for (int j = 0; j < 4; ++j) {
        const int d = j * 256 + lane * 4;
        q4[j]  = *reinterpret_cast<const float4*>(qrow + d);
        w2r[j] = *reinterpret_cast<const float4*>(weight + 2 * DCONST + d);
        float4 w3 = *reinterpret_cast<const float4*>(weight + 3 * DCONST + d);
        float4 w1 = *reinterpret_cast<const float4*>(weight + 1 * DCONST + d);
        qw3[j] = make_float4(q4[j].x * w3.x, q4[j].y * w3.y,
                             q4[j].z * w3.z, q4[j].w * w3.w);
        tq += q4[j].x * w1.x + q4[j].y * w1.y + q4[j].z * w1.z + q4[j].w * w1.w;
    }
#pragma unroll
    for (int off = 32; off; off >>= 1) tq += __shfl_xor(tq, off, 64);
    const float cbase = tq + bias[0];

    const float* pbase = proto + ((size_t)(b * NPROTO) + half * NHALF) * DCONST;

    float acc[NHALF];
#pragma unroll
    for (int n = 0; n < NHALF; ++n) acc[n] = 0.f;

#pragma unroll
    for (int n = 0; n < NHALF; ++n) {
        const float* prow = pbase + (size_t)n * DCONST;
#pragma unroll
        for (int j = 0; j < 4; ++j) {
            const int d = j * 256 + lane * 4;
            float4 p = *reinterpret_cast<const float4*>(prow + d);
            float a = acc[n];
            a = fmaf(fabsf(p.x - q4[j].x), w2r[j].x, a);
            a = fmaf(qw3[j].x, p.x, a);
            a = fmaf(fabsf(p.y - q4[j].y), w2r[j].y, a);
            a = fmaf(qw3[j].y, p.y, a);
            a = fmaf(fabsf(p.z - q4[j].z), w2r[j].z, a);
            a = fmaf(qw3[j].z, p.z, a);
            a = fmaf(fabsf(p.w - q4[j].w), w2r[j].w, a);
            a = fmaf(qw3[j].w, p.w, a);
            acc[n] = a;
        }
    }

    // 10 independent butterfly trees; every lane ends with the full sum,
    // lane n keeps tree n's result.
    float myval = 0.f;
#pragma unroll
    for (int n = 0; n < NHALF; ++n) {
        float r = acc[n];
#pragma unroll
        for (int off = 32; off; off >>= 1) r += __shfl_xor(r, off, 64);
        if (lane == n) myval = r;
    }

    if (lane < NHALF) {
        const int n = half * NHALF + lane;
        out[((size_t)b * NQ + qp) * NPROTO + n] =
            myval + cbase + term_p[b * NPROTO + n];
    }
}

extern "C" void kernel_launch(void* const* d_in, const int* in_sizes, int n_in,
                              void* d_out, int out_size, void* d_ws, size_t ws_size,
                              hipStream_t stream) {
    const float* emb    = (const float*)d_in[0];
    const float* weight = (const float*)d_in[1];
    const float* bias   = (const float*)d_in[2];
    float* out = (float*)d_out;

    const int B = in_sizes[0] / (NPROTO * SLOTS * DCONST);   // 8

    float* proto  = (float*)d_ws;                              // B*N*D floats
    float* term_p = proto + (size_t)B * NPROTO * DCONST;       // B*N floats

    proto_kernel<<<B * NPROTO, 256, 0, stream>>>(emb, weight, proto, term_p);

    logits_kernel<<<B * (NQ / 4) * 2, 256, 0, stream>>>(emb, weight, bias,
                                                        proto, term_p, out);
}

// Round 3
// 82.511 us; speedup vs baseline: 1.0195x; 1.0195x over previous
//
#include <hip/hip_runtime.h>

// Problem constants from setup_inputs(): B=8, N=20, K=5, Q=15, D=1024.
#define DCONST 1024
#define KSUP 5
#define NPROTO 20
#define QPER 15
#define SLOTS (KSUP + QPER)   // 20
#define NQ (NPROTO * QPER)    // 300
#define NHALF (NPROTO / 2)    // 10
#define GROWS 12              // q-rows per block (3 per wave)

// Single fused kernel.
// grid = B * 2 * (NQ/GROWS) = 8*2*25 = 400 blocks, 256 threads (4 waves).
// Each block: stages its 10 protos (mean of 5 support rows) into LDS once,
// then each wave computes 3 query rows against all 10 LDS protos.
// term_p is folded into the accumulation (acc += p*w0), term_q is a per-row
// wave reduce. All cross-lane reduces are batched butterflies at row end.
__global__ __launch_bounds__(256, 2) void relnet_fused_kernel(
    const float* __restrict__ emb,     // (B, N, K+Q, D)
    const float* __restrict__ weight,  // (4, D)
    const float* __restrict__ bias,    // (1,)
    float* __restrict__ out)           // (B, N*Q, NPROTO)
{
    __shared__ float sproto[NHALF][DCONST];   // 40 KiB

    const int tid  = threadIdx.x;
    const int lane = tid & 63;
    const int wid  = tid >> 6;

    const int groups_per_b = NQ / GROWS;               // 25
    const int b    = blockIdx.x / (2 * groups_per_b);
    const int rem  = blockIdx.x % (2 * groups_per_b);
    const int half = rem / groups_per_b;               // which 10 protos
    const int grp  = rem % groups_per_b;

    // ---- per-thread weight slices (independent of LDS; issue early) ----
    float4 w0r[4], w1r[4], w2r[4], w3r[4];
#pragma unroll
    for (int j = 0; j < 4; ++j) {
        const int d = j * 256 + lane * 4;
        w0r[j] = *reinterpret_cast<const float4*>(weight + 0 * DCONST + d);
        w1r[j] = *reinterpret_cast<const float4*>(weight + 1 * DCONST + d);
        w2r[j] = *reinterpret_cast<const float4*>(weight + 2 * DCONST + d);
        w3r[j] = *reinterpret_cast<const float4*>(weight + 3 * DCONST + d);
    }
    const float bias0 = bias[0];

    // ---- stage 10 protos into LDS (256 threads cover 1024 d as float4) ----
    const int d0 = tid * 4;   // 0..1020
#pragma unroll
    for (int n = 0; n < NHALF; ++n) {
        const float* base =
            emb + ((size_t)((b * NPROTO + half * NHALF + n) * SLOTS)) * DCONST + d0;
        float4 s = make_float4(0.f, 0.f, 0.f, 0.f);
#pragma unroll
        for (int k = 0; k < KSUP; ++k) {
            float4 v = *reinterpret_cast<const float4*>(base + (size_t)k * DCONST);
            s.x += v.x; s.y += v.y; s.z += v.z; s.w += v.w;
        }
        s.x *= 0.2f; s.y *= 0.2f; s.z *= 0.2f; s.w *= 0.2f;
        *reinterpret_cast<float4*>(&sproto[n][d0]) = s;
    }
    __syncthreads();

    // ---- each wave: 3 query rows ----
#pragma unroll
    for (int r = 0; r < 3; ++r) {
        const int qp   = grp * GROWS + wid * 3 + r;   // 0..299
        const int nsrc = qp / QPER;
        const int qq   = qp % QPER;
        const float* qrow =
            emb + (((size_t)(b * NPROTO + nsrc) * SLOTS) + KSUP + qq) * DCONST;

        float4 q4[4], qw3[4];
        float tq = 0.f;
#pragma unroll
        for (int j = 0; j < 4; ++j) {
            const int d = j * 256 + lane * 4;
            q4[j] = *reinterpret_cast<const float4*>(qrow + d);
            qw3[j] = make_float4(q4[j].x * w3r[j].x, q4[j].y * w3r[j].y,
                                 q4[j].z * w3r[j].z, q4[j].w * w3r[j].w);
            tq += q4[j].x * w1r[j].x + q4[j].y * w1r[j].y +
                  q4[j].z * w1r[j].z + q4[j].w * w1r[j].w;
        }
#pragma unroll
        for (int off = 32; off; off >>= 1) tq += __shfl_xor(tq, off, 64);
        const float cbase = tq + bias0;

        float acc[NHALF];
#pragma unroll
        for (int n = 0; n < NHALF; ++n) acc[n] = 0.f;

#pragma unroll
        for (int n = 0; n < NHALF; ++n) {
#pragma unroll
            for (int j = 0; j < 4; ++j) {
                const float4 p =
                    *reinterpret_cast<const float4*>(&sproto[n][j * 256 + lane * 4]);
                float a = acc[n];
                a = fmaf(fabsf(p.x - q4[j].x), w2r[j].x, a);
                a = fmaf(qw3[j].x, p.x, a);
                a = fmaf(p.x, w0r[j].x, a);            // folds term_p
                a = fmaf(fabsf(p.y - q4[j].y), w2r[j].y, a);
                a = fmaf(qw3[j].y, p.y, a);
                a = fmaf(p.y, w0r[j].y, a);
                a = fmaf(fabsf(p.z - q4[j].z), w2r[j].z, a);
                a = fmaf(qw3[j].z, p.z, a);
                a = fmaf(p.z, w0r[j].z, a);
                a = fmaf(fabsf(p.w - q4[j].w), w2r[j].w, a);
                a = fmaf(qw3[j].w, p.w, a);
                a = fmaf(p.w, w0r[j].w, a);
                acc[n] = a;
            }
        }

        // 10 independent butterfly trees; lane n keeps tree n's total.
        float myval = 0.f;
#pragma unroll
        for (int n = 0; n < NHALF; ++n) {
            float v = acc[n];
#pragma unroll
            for (int off = 32; off; off >>= 1) v += __shfl_xor(v, off, 64);
            if (lane == n) myval = v;
        }

        if (lane < NHALF) {
            out[((size_t)b * NQ + qp) * NPROTO + half * NHALF + lane] =
                myval + cbase;
        }
    }
}

extern "C" void kernel_launch(void* const* d_in, const int* in_sizes, int n_in,
                              void* d_out, int out_size, void* d_ws, size_t ws_size,
                              hipStream_t stream) {
    const float* emb    = (const float*)d_in[0];
    const float* weight = (const float*)d_in[1];
    const float* bias   = (const float*)d_in[2];
    float* out = (float*)d_out;

    const int B = in_sizes[0] / (NPROTO * SLOTS * DCONST);   // 8
    const int groups_per_b = NQ / GROWS;                     // 25

    relnet_fused_kernel<<<B * 2 * groups_per_b, 256, 0, stream>>>(
        emb, weight, bias, out);
}